// Round 3
// baseline (528.001 us; speedup 1.0000x reference)
//
#include <hip/hip_runtime.h>

#define N_ROWS 32768
#define DIM 256
#define KCODES 1024

#define Q_N (N_ROWS * DIM)          // 8388608
#define IDX_OFF Q_N                 // 8388608
#define ZERO_OFF (Q_N + N_ROWS)     // 8421376
#define LOSS_OFF (ZERO_OFF + 1)
#define PERP_OFF (ZERO_OFF + 2)

// margin below which np's ulp(~256)-grid quantization could create a tie
#define THETA 1.3e-4f

// ws layout (bytes):
//   [0, 4096)          sen float[K]        (accurate fp32 of ||e||^2)
//   [4096, 8192)       hist uint[K]
//   [8192, 8200)       double loss_acc
//   [8200, 8204)       uint ambig_count
//   [8448, 139520)     szn float[32768]    (numpy-pairwise-emulated ||z||^2)
//   [139520, 270592)   uint worklist[32768]
__global__ __launch_bounds__(1024) void vq_init(unsigned* __restrict__ hist,
                                                double* __restrict__ loss_acc,
                                                unsigned* __restrict__ count) {
    int t = threadIdx.x;
    if (t < KCODES) hist[t] = 0u;
    if (t == 0) { *loss_acc = 0.0; *count = 0u; }
}

// accurate ||e_k||^2: fp64 accumulate -> fp32 (error ~1e-16, far below ulp boundaries)
__global__ __launch_bounds__(256) void vq_sen(const float* __restrict__ cb,
                                              float* __restrict__ sen) {
    int w = blockIdx.x * 4 + (threadIdx.x >> 6);
    int lane = threadIdx.x & 63;
    float4 v = *(const float4*)(cb + (size_t)w * DIM + lane * 4);
    double s = (double)v.x * v.x + (double)v.y * v.y + (double)v.z * v.z + (double)v.w * v.w;
    #pragma unroll
    for (int off = 32; off; off >>= 1) s += __shfl_down(s, off, 64);
    if (lane == 0) sen[w] = (float)s;
}

// ||z_row||^2 emulating numpy fp32 pairwise_sum for n=256:
//   S = block128(a[0:128]) + block128(a[128:256])
//   block128: r[j]=a[j]; for i=8..120 step 8: r[j]+=a[i+j];
//             res = ((r0+r1)+(r2+r3))+((r4+r5)+(r6+r7))
// a[d] = fl32(z_d * z_d). All roundings forced via __fmul_rn/__fadd_rn
// (hipcc contract=fast must not fuse).
__global__ __launch_bounds__(256) void vq_szn(const float* __restrict__ z,
                                              float* __restrict__ szn) {
    int lane = threadIdx.x & 63;
    int waveInBlk = threadIdx.x >> 6;
    int rowInWave = lane >> 4;   // 4 rows / wave
    int sub = lane & 15;         // 16 lanes / row
    int h = sub >> 3;            // which 128-block
    int j = sub & 7;             // accumulator index
    int row = (blockIdx.x * 4 + waveInBlk) * 4 + rowInWave;
    const float* a = z + (size_t)row * DIM + h * 128 + j;
    float v0 = a[0];
    float c = __fmul_rn(v0, v0);
    #pragma unroll
    for (int i = 1; i < 16; ++i) {
        float v = a[8 * i];
        c = __fadd_rn(c, __fmul_rn(v, v));
    }
    // fixed combine tree: ((r0+r1)+(r2+r3))+((r4+r5)+(r6+r7)), then S1+S2
    float p;
    p = __shfl_xor(c, 1, 64); c = __fadd_rn(c, p);
    p = __shfl_xor(c, 2, 64); c = __fadd_rn(c, p);
    p = __shfl_xor(c, 4, 64); c = __fadd_rn(c, p);
    p = __shfl_xor(c, 8, 64); c = __fadd_rn(c, p);
    if (sub == 0) szn[row] = c;
}

// fast fp32 pass: 64 rows x 128 codes tile; top-2 per row; margin < THETA -> worklist
__global__ __launch_bounds__(256) void vq_argmin(const float* __restrict__ z,
                                                 const float* __restrict__ cb,
                                                 const float* __restrict__ sen,
                                                 float* __restrict__ idx_out,
                                                 unsigned* __restrict__ count,
                                                 unsigned* __restrict__ worklist) {
    __shared__ float zs[32][68];
    __shared__ float es[32][132];
    const int tid = threadIdx.x;
    const int tx = tid & 15;   // code group (8 codes each)
    const int ty = tid >> 4;   // row group (4 rows each)
    const int r0 = blockIdx.x * 64;

    float best[4]   = {3.4e38f, 3.4e38f, 3.4e38f, 3.4e38f};
    float second[4] = {3.4e38f, 3.4e38f, 3.4e38f, 3.4e38f};
    int   besti[4]  = {0, 0, 0, 0};

    for (int c0 = 0; c0 < KCODES; c0 += 128) {
        float acc[4][8];
        #pragma unroll
        for (int rr = 0; rr < 4; ++rr)
            #pragma unroll
            for (int u = 0; u < 8; ++u) acc[rr][u] = 0.f;

        for (int d0 = 0; d0 < DIM; d0 += 32) {
            #pragma unroll
            for (int i = 0; i < 2; ++i) {
                int v = tid + i * 256;
                int row = v >> 3, q = v & 7;
                float4 zv = *(const float4*)(z + (size_t)(r0 + row) * DIM + d0 + q * 4);
                zs[q * 4 + 0][row] = zv.x;
                zs[q * 4 + 1][row] = zv.y;
                zs[q * 4 + 2][row] = zv.z;
                zs[q * 4 + 3][row] = zv.w;
            }
            #pragma unroll
            for (int i = 0; i < 4; ++i) {
                int v = tid + i * 256;
                int cI = v >> 3, q = v & 7;
                float4 ev = *(const float4*)(cb + (size_t)(c0 + cI) * DIM + d0 + q * 4);
                es[q * 4 + 0][cI] = ev.x;
                es[q * 4 + 1][cI] = ev.y;
                es[q * 4 + 2][cI] = ev.z;
                es[q * 4 + 3][cI] = ev.w;
            }
            __syncthreads();
            #pragma unroll 8
            for (int d = 0; d < 32; ++d) {
                float4 zf = *(const float4*)&zs[d][ty * 4];
                float4 e0 = *(const float4*)&es[d][tx * 8];
                float4 e1 = *(const float4*)&es[d][tx * 8 + 4];
                float zr[4] = {zf.x, zf.y, zf.z, zf.w};
                float er[8] = {e0.x, e0.y, e0.z, e0.w, e1.x, e1.y, e1.z, e1.w};
                #pragma unroll
                for (int rr = 0; rr < 4; ++rr)
                    #pragma unroll
                    for (int u = 0; u < 8; ++u)
                        acc[rr][u] = fmaf(zr[rr], er[u], acc[rr][u]);
            }
            __syncthreads();
        }

        #pragma unroll
        for (int rr = 0; rr < 4; ++rr) {
            float v1 = 3.4e38f, v2 = 3.4e38f;
            int i1 = 0;
            #pragma unroll
            for (int u = 0; u < 8; ++u) {
                int cI = c0 + tx * 8 + u;
                float s = sen[cI] - 2.0f * acc[rr][u];
                if (s < v1) { v2 = v1; v1 = s; i1 = cI; }
                else if (s < v2) { v2 = s; }
            }
            #pragma unroll
            for (int m = 1; m < 16; m <<= 1) {
                float ov1 = __shfl_xor(v1, m, 64);
                int   oi1 = __shfl_xor(i1, m, 64);
                float ov2 = __shfl_xor(v2, m, 64);
                if (ov1 < v1 || (ov1 == v1 && oi1 < i1)) {
                    v2 = fminf(v1, ov2); v1 = ov1; i1 = oi1;
                } else {
                    v2 = fminf(v2, ov1);
                }
            }
            if (v1 < best[rr] || (v1 == best[rr] && i1 < besti[rr])) {
                second[rr] = fminf(best[rr], v2);
                best[rr] = v1; besti[rr] = i1;
            } else {
                second[rr] = fminf(second[rr], v1);
            }
        }
    }

    if (tx == 0) {
        #pragma unroll
        for (int rr = 0; rr < 4; ++rr) {
            int row = r0 + ty * 4 + rr;
            idx_out[row] = (float)besti[rr];
            if (second[rr] - best[rr] < THETA) {
                unsigned slot = atomicAdd(count, 1u);
                worklist[slot] = (unsigned)row;
            }
        }
    }
}

// np-fp32 emulation for ambiguous rows:
//   d_k = fl32( fl32(szn + sen_k) - 2*fl32(dot_k) ), dot_k from fp64
//   argmin with first-index tie-break == np.argmin of the reference's d matrix
__global__ __launch_bounds__(256) void vq_fixup(const float* __restrict__ z,
                                                const float* __restrict__ cb,
                                                const float* __restrict__ sen,
                                                const float* __restrict__ szn,
                                                const unsigned* __restrict__ count,
                                                const unsigned* __restrict__ worklist,
                                                float* __restrict__ idx_out) {
    __shared__ float zrow[DIM];
    __shared__ float rv[256];
    __shared__ int ri[256];
    int t = threadIdx.x;
    int n = (int)*count;
    for (int w = blockIdx.x; w < n; w += gridDim.x) {
        int row = (int)worklist[w];
        float sz = szn[row];
        zrow[t] = z[(size_t)row * DIM + t];
        __syncthreads();
        float bv = 3.4e38f;
        int bi = 0x7fffffff;
        #pragma unroll
        for (int cc = 0; cc < 4; ++cc) {
            int cI = t + 256 * cc;                // ascending within thread
            const float* e = cb + (size_t)cI * DIM;
            double dot = 0.0;
            for (int d = 0; d < DIM; d += 4) {
                float4 ev = *(const float4*)(e + d);
                dot += (double)ev.x * zrow[d + 0] + (double)ev.y * zrow[d + 1]
                     + (double)ev.z * zrow[d + 2] + (double)ev.w * zrow[d + 3];
            }
            float dotx = (float)dot;
            float A = __fadd_rn(sz, sen[cI]);     // fl(szn + sen_k)
            float dref = __fmaf_rn(-2.0f, dotx, A); // == fl(A - fl(2*dotx)), 2*dotx exact
            if (dref < bv) { bv = dref; bi = cI; }
        }
        rv[t] = bv; ri[t] = bi;
        __syncthreads();
        for (int s = 128; s; s >>= 1) {
            if (t < s) {
                if (rv[t + s] < rv[t] || (rv[t + s] == rv[t] && ri[t + s] < ri[t])) {
                    rv[t] = rv[t + s]; ri[t] = ri[t + s];
                }
            }
            __syncthreads();
        }
        if (t == 0) idx_out[row] = (float)ri[0];
        __syncthreads();
    }
}

// quantized_ste = z + (q - z); commitment loss; histogram from final idx
__global__ __launch_bounds__(256) void vq_gather(const float* __restrict__ z,
                                                 const float* __restrict__ cb,
                                                 const float* __restrict__ idxf,
                                                 float* __restrict__ qout,
                                                 double* __restrict__ loss_acc,
                                                 unsigned* __restrict__ hist) {
    int gid = blockIdx.x * 256 + threadIdx.x;
    int row = gid >> 6, c4 = gid & 63;
    int idx = (int)idxf[row];
    if (c4 == 0) atomicAdd(&hist[idx], 1u);
    float4 zv = *(const float4*)(z + (size_t)row * DIM + c4 * 4);
    float4 qv = *(const float4*)(cb + (size_t)idx * DIM + c4 * 4);
    float dx = qv.x - zv.x, dy = qv.y - zv.y, dz = qv.z - zv.z, dw = qv.w - zv.w;
    float4 o;
    o.x = zv.x + dx; o.y = zv.y + dy; o.z = zv.z + dz; o.w = zv.w + dw;
    *(float4*)(qout + (size_t)row * DIM + c4 * 4) = o;
    float ls = dx * dx + dy * dy + dz * dz + dw * dw;
    #pragma unroll
    for (int off = 32; off; off >>= 1) ls += __shfl_down(ls, off, 64);
    __shared__ float wsum[4];
    int lane = threadIdx.x & 63, wv = threadIdx.x >> 6;
    if (lane == 0) wsum[wv] = ls;
    __syncthreads();
    if (threadIdx.x == 0)
        atomicAdd(loss_acc, (double)(wsum[0] + wsum[1] + wsum[2] + wsum[3]));
}

__global__ __launch_bounds__(1024) void vq_finalize(const unsigned* __restrict__ hist,
                                                    const double* __restrict__ loss_acc,
                                                    float* __restrict__ out) {
    __shared__ float red[1024];
    int t = threadIdx.x;
    float p = (float)hist[t] * (1.0f / (float)N_ROWS);
    red[t] = p * logf(p + 1e-10f);
    __syncthreads();
    for (int s = 512; s; s >>= 1) {
        if (t < s) red[t] += red[t + s];
        __syncthreads();
    }
    if (t == 0) {
        out[ZERO_OFF] = 0.0f;
        out[LOSS_OFF] = (float)(0.25 * (*loss_acc) / (double)Q_N);
        out[PERP_OFF] = expf(-red[0]);
    }
}

extern "C" void kernel_launch(void* const* d_in, const int* in_sizes, int n_in,
                              void* d_out, int out_size, void* d_ws, size_t ws_size,
                              hipStream_t stream) {
    const float* z = (const float*)d_in[0];
    const float* cb = (const float*)d_in[1];
    float* out = (float*)d_out;
    float* sen = (float*)d_ws;
    unsigned* hist = (unsigned*)((char*)d_ws + 4096);
    double* loss_acc = (double*)((char*)d_ws + 8192);
    unsigned* count = (unsigned*)((char*)d_ws + 8200);
    float* szn = (float*)((char*)d_ws + 8448);
    unsigned* worklist = (unsigned*)((char*)d_ws + 139520);

    vq_init<<<1, 1024, 0, stream>>>(hist, loss_acc, count);
    vq_sen<<<KCODES / 4, 256, 0, stream>>>(cb, sen);
    vq_szn<<<N_ROWS / 16, 256, 0, stream>>>(z, szn);
    vq_argmin<<<N_ROWS / 64, 256, 0, stream>>>(z, cb, sen, out + IDX_OFF, count, worklist);
    vq_fixup<<<256, 256, 0, stream>>>(z, cb, sen, szn, count, worklist, out + IDX_OFF);
    vq_gather<<<(N_ROWS * (DIM / 4)) / 256, 256, 0, stream>>>(z, cb, out + IDX_OFF, out, loss_acc, hist);
    vq_finalize<<<1, 1024, 0, stream>>>(hist, loss_acc, out);
}